// Round 4
// baseline (501.107 us; speedup 1.0000x reference)
//
#include <hip/hip_runtime.h>
#include <hip/hip_bf16.h>

#define THREADS 256

typedef short bf16x8 __attribute__((ext_vector_type(8)));
typedef float f32x16 __attribute__((ext_vector_type(16)));

__device__ __forceinline__ unsigned short f2bf(float x) {
    unsigned u = __float_as_uint(x);
    return (unsigned short)((u + 0x7FFFu + ((u >> 16) & 1u)) >> 16);
}
__device__ __forceinline__ float bf2f(unsigned short h) {
    return __uint_as_float(((unsigned)h) << 16);
}
__device__ __forceinline__ unsigned score_key(float s) {
    unsigned u = __float_as_uint(s);
    return (u & 0x80000000u) ? ~u : (u | 0x80000000u);
}

// native-cast split: f32[8] -> bf16 hi + bf16 lo (compiler emits v_cvt_pk_bf16_f32)
__device__ __forceinline__ void split8n(const float4& fa, const float4& fb,
                                        bf16x8& hv, bf16x8& lv) {
    const float f[8] = {fa.x, fa.y, fa.z, fa.w, fb.x, fb.y, fb.z, fb.w};
    union { unsigned short u[8]; bf16x8 v; } H, L;
#pragma unroll
    for (int j = 0; j < 8; ++j) {
        __hip_bfloat16 hb = __float2bfloat16(f[j]);
        const unsigned short hr = reinterpret_cast<const unsigned short&>(hb);
        const float hf = __uint_as_float(((unsigned)hr) << 16);
        __hip_bfloat16 lb = __float2bfloat16(f[j] - hf);
        H.u[j] = hr;
        L.u[j] = reinterpret_cast<const unsigned short&>(lb);
    }
    hv = H.v; lv = L.v;
}

__device__ __forceinline__ void async_cp16(const uint4* g, uint4* l) {
    __builtin_amdgcn_global_load_lds(
        (const __attribute__((address_space(1))) unsigned int*)g,
        (__attribute__((address_space(3))) unsigned int*)l, 16, 0, 0);
}

// v[j] = sum_o W2[j,o]*Ws[o];  v[256] = dot(b2,Ws) + bs
__global__ void prep_kernel(const float* __restrict__ W2, const float* __restrict__ b2,
                            const float* __restrict__ Ws, const float* __restrict__ bs,
                            float* __restrict__ v, int OUT) {
    int j = threadIdx.x;
    float acc = 0.f;
    for (int o = 0; o < OUT; ++o) acc += W2[j * OUT + o] * Ws[o];
    v[j] = acc;
    if (j == 0) {
        float c = bs[0];
        for (int o = 0; o < OUT; ++o) c += b2[o] * Ws[o];
        v[256] = c;
    }
}

// W1 [256][256] -> 32x32x16 fragment pack, hi/lo.
// uint4 idx = kt*2048 + (hl*16 + nt*2 + kc)*64 + lane
// elem j of slot = W1[kt*32 + kc*16 + (lane>>5)*8 + j][nt*32 + (lane&31)]
__global__ void prep_w1frag(const float* __restrict__ W1, uint4* __restrict__ wfrag) {
    const int s = blockIdx.x * 256 + threadIdx.x;   // 0..16383
    const int kt = s >> 11;
    const int c = (s >> 6) & 31;
    const int lane = s & 63;
    const int hl = c >> 4;
    const int nt = (c >> 1) & 7;
    const int kc = c & 1;
    const int col = nt * 32 + (lane & 31);
    const int k0 = kt * 32 + kc * 16 + (lane >> 5) * 8;
    unsigned pk[4];
#pragma unroll
    for (int q = 0; q < 4; ++q) {
        float x0 = W1[(size_t)(k0 + 2 * q) * 256 + col];
        float x1 = W1[(size_t)(k0 + 2 * q + 1) * 256 + col];
        unsigned short a0, a1;
        if (hl == 0) { a0 = f2bf(x0); a1 = f2bf(x1); }
        else {
            a0 = f2bf(x0 - bf2f(f2bf(x0)));
            a1 = f2bf(x1 - bf2f(f2bf(x1)));
        }
        pk[q] = (unsigned)a0 | ((unsigned)a1 << 16);
    }
    wfrag[s] = make_uint4(pk[0], pk[1], pk[2], pk[3]);
}

__global__ void init_bins(unsigned long long* __restrict__ bins, int n) {
    int i = blockIdx.x * blockDim.x + threadIdx.x;
    if (i < n) bins[i] = 0ULL;
}

// Fused: h = desc@W1 + b1 (bf16x4-split 32x32x16 MFMA); LN; SiLU; score; gid; bin argmax
// 4 waves/block; wave owns 32 rows x 256 cols. A direct-from-global, B async LDS dbuf.
__global__ __launch_bounds__(256, 2) void score_kernel(
    const float* __restrict__ desc, const float* __restrict__ kpts,
    const uint4* __restrict__ wfrag,
    const float* __restrict__ b1, const float* __restrict__ g1, const float* __restrict__ be1,
    const int* __restrict__ Hp, const int* __restrict__ Wp,
    const float* __restrict__ v,
    float* __restrict__ scores, unsigned long long* __restrict__ bins,
    int N, int total)
{
    __shared__ uint4 BS[2][32 * 64];   // double-buffered W1 frags (2 x 32KB)
    __shared__ float b1L[256], g1L[256], beL[256], vL[256];

    const int t = threadIdx.x;
    const int lane = t & 63;
    const int w = t >> 6;                 // wave 0..3
    const int c31 = lane & 31;            // A-row within wave / B-col within chunk
    const int h = lane >> 5;              // k-half selector
    const int wrow0 = blockIdx.x * 128 + w * 32;

    b1L[t] = b1[t]; g1L[t] = g1[t]; beL[t] = be1[t]; vL[t] = v[t];

    // issue B[kt=0] into BS[0] (wave w stages chunks w*8 .. w*8+7)
    {
        const uint4* bsrc = wfrag + (w * 8) * 64 + lane;
#pragma unroll
        for (int j = 0; j < 8; ++j)
            async_cp16(bsrc + j * 64, &BS[0][(w * 8 + j) * 64]);
    }

    // A: thread covers row (wrow0 + c31), k-slots (h*8 + j) of each 16-k chunk
    const int rA = min(wrow0 + c31, total - 1);
    const float* pa = desc + (size_t)rA * 256 + h * 8;
    float4 aA = *(const float4*)(pa + 0);
    float4 aB = *(const float4*)(pa + 4);
    float4 aC = *(const float4*)(pa + 16);
    float4 aD = *(const float4*)(pa + 20);

    __syncthreads();   // drains vmcnt: B[0] in LDS, param LDS visible

    f32x16 acc[8];
#pragma unroll
    for (int nt = 0; nt < 8; ++nt) {
        const float bc = b1L[nt * 32 + c31];   // fold b1 into acc init (col-constant)
#pragma unroll
        for (int r = 0; r < 16; ++r) acc[nt][r] = bc;
    }

    for (int kt = 0; kt < 8; ++kt) {
        const int cur = kt & 1;
        // prefetch B[kt+1] (async, drained at end-of-kt barrier)
        if (kt < 7) {
            const uint4* bsrc = wfrag + (size_t)(kt + 1) * 2048 + (w * 8) * 64 + lane;
#pragma unroll
            for (int j = 0; j < 8; ++j)
                async_cp16(bsrc + j * 64, &BS[cur ^ 1][(w * 8 + j) * 64]);
        }
        float4 nA, nB, nC, nD;
        if (kt < 7) {   // prefetch next A (covered by this kt's MFMA)
            const float* q = pa + (kt + 1) * 32;
            nA = *(const float4*)(q + 0);  nB = *(const float4*)(q + 4);
            nC = *(const float4*)(q + 16); nD = *(const float4*)(q + 20);
        }
        // ---- kc = 0
        {
            bf16x8 ah, al;
            split8n(aA, aB, ah, al);
            bf16x8 bq[8];
#pragma unroll
            for (int nt = 0; nt < 8; ++nt)
                bq[nt] = *(const bf16x8*)&BS[cur][(nt * 2 + 0) * 64 + lane];      // hi
            __builtin_amdgcn_s_setprio(1);
#pragma unroll
            for (int nt = 0; nt < 8; ++nt)
                acc[nt] = __builtin_amdgcn_mfma_f32_32x32x16_bf16(ah, bq[nt], acc[nt], 0, 0, 0);
#pragma unroll
            for (int nt = 0; nt < 8; ++nt)
                acc[nt] = __builtin_amdgcn_mfma_f32_32x32x16_bf16(al, bq[nt], acc[nt], 0, 0, 0);
            __builtin_amdgcn_s_setprio(0);
#pragma unroll
            for (int nt = 0; nt < 8; ++nt)
                bq[nt] = *(const bf16x8*)&BS[cur][(16 + nt * 2 + 0) * 64 + lane]; // lo
            __builtin_amdgcn_s_setprio(1);
#pragma unroll
            for (int nt = 0; nt < 8; ++nt)
                acc[nt] = __builtin_amdgcn_mfma_f32_32x32x16_bf16(ah, bq[nt], acc[nt], 0, 0, 0);
#pragma unroll
            for (int nt = 0; nt < 8; ++nt)
                acc[nt] = __builtin_amdgcn_mfma_f32_32x32x16_bf16(al, bq[nt], acc[nt], 0, 0, 0);
            __builtin_amdgcn_s_setprio(0);
        }
        // ---- kc = 1
        {
            bf16x8 ah, al;
            split8n(aC, aD, ah, al);
            bf16x8 bq[8];
#pragma unroll
            for (int nt = 0; nt < 8; ++nt)
                bq[nt] = *(const bf16x8*)&BS[cur][(nt * 2 + 1) * 64 + lane];      // hi
            __builtin_amdgcn_s_setprio(1);
#pragma unroll
            for (int nt = 0; nt < 8; ++nt)
                acc[nt] = __builtin_amdgcn_mfma_f32_32x32x16_bf16(ah, bq[nt], acc[nt], 0, 0, 0);
#pragma unroll
            for (int nt = 0; nt < 8; ++nt)
                acc[nt] = __builtin_amdgcn_mfma_f32_32x32x16_bf16(al, bq[nt], acc[nt], 0, 0, 0);
            __builtin_amdgcn_s_setprio(0);
#pragma unroll
            for (int nt = 0; nt < 8; ++nt)
                bq[nt] = *(const bf16x8*)&BS[cur][(16 + nt * 2 + 1) * 64 + lane]; // lo
            __builtin_amdgcn_s_setprio(1);
#pragma unroll
            for (int nt = 0; nt < 8; ++nt)
                acc[nt] = __builtin_amdgcn_mfma_f32_32x32x16_bf16(ah, bq[nt], acc[nt], 0, 0, 0);
#pragma unroll
            for (int nt = 0; nt < 8; ++nt)
                acc[nt] = __builtin_amdgcn_mfma_f32_32x32x16_bf16(al, bq[nt], acc[nt], 0, 0, 0);
            __builtin_amdgcn_s_setprio(0);
        }
        aA = nA; aB = nB; aC = nC; aD = nD;
        __syncthreads();   // next B buffer ready
    }

    // ---- epilogue: LN + SiLU + score. C/D: row=(reg&3)+8*(reg>>2)+4*h, col=nt*32+c31
    const float Wf = (float)Wp[0];
    const int Hi = Hp[0];
    const float t02 = (float)(0.2 * (double)Hi);
    const float t05 = (float)(0.5 * (double)Hi);
    const float t03 = (float)(0.3 * (double)Hi);
    const float cterm = v[256];

#pragma unroll
    for (int reg = 0; reg < 16; ++reg) {
        float sx = 0.f, sq = 0.f;
#pragma unroll
        for (int nt = 0; nt < 8; ++nt) {
            const float x = acc[nt][reg];
            sx += x; sq = fmaf(x, x, sq);
        }
#pragma unroll
        for (int m = 1; m <= 16; m <<= 1) {
            sx += __shfl_xor(sx, m);
            sq += __shfl_xor(sq, m);
        }
        const float mu = sx * (1.f / 256.f);
        const float var = sq * (1.f / 256.f) - mu * mu;
        const float rs = 1.f / sqrtf(var + 1e-5f);
        float dot = 0.f;
#pragma unroll
        for (int nt = 0; nt < 8; ++nt) {
            const int c = nt * 32 + c31;
            const float hv = (acc[nt][reg] - mu) * rs * g1L[c] + beL[c];
            const float sg = 1.f / (1.f + __expf(-hv));
            dot = fmaf(vL[c], hv * sg, dot);
        }
#pragma unroll
        for (int m = 1; m <= 16; m <<= 1) dot += __shfl_xor(dot, m);

        if (c31 == 0) {
            const int row = wrow0 + (reg & 3) + 8 * (reg >> 2) + 4 * h;
            if (row < total) {
                const float sc = dot + cterm;
                scores[row] = sc;
                const float x = kpts[(size_t)row * 2 + 0];
                const float y = kpts[(size_t)row * 2 + 1];
                int g = -1;
                if (y > t05) {
                    int bgx = (int)(x / Wf * 16.f); bgx = min(max(bgx, 0), 15);
                    int bgy = (int)((y - t05) / t05 * 6.f); bgy = min(max(bgy, 0), 5);
                    g = 32 + bgy * 16 + bgx;
                } else if (y > t02) {
                    int mgx = (int)(x / Wf * 8.f); mgx = min(max(mgx, 0), 7);
                    int mgy = (int)((y - t02) / t03 * 4.f); mgy = min(max(mgy, 0), 3);
                    g = mgy * 8 + mgx;
                }
                if (g >= 0) {
                    const int bb = row / N;
                    const int n = row - bb * N;
                    const unsigned long long pk =
                        ((unsigned long long)score_key(sc) << 32) | (unsigned)(~(unsigned)n);
                    atomicMax(&bins[bb * 128 + g], pk);
                }
            }
        }
    }
}

// One block per batch: compact bin winners (bin order), top-k fallback, gather outputs.
__global__ __launch_bounds__(256) void finalize_kernel(
    const float* __restrict__ scores, const unsigned long long* __restrict__ bins,
    const float* __restrict__ desc, const float* __restrict__ kpts,
    const int* __restrict__ tkp, float* __restrict__ out, int B, int N)
{
    const int b = blockIdx.x, t = threadIdx.x;
    const int topk = tkp[0];
    __shared__ int selL[512];
    __shared__ int nselS;
    __shared__ unsigned long long red[256];
    __shared__ unsigned long long binL[128];

    if (t < 128) binL[t] = bins[b * 128 + t];
    __syncthreads();
    if (t == 0) {
        int c = 0;
        for (int i = 0; i < 128; ++i)
            if ((binL[i] >> 32) != 0ULL) selL[c++] = (int)(~(unsigned)binL[i]);
        nselS = c;
    }
    __syncthreads();
    const int nsel = nselS;

    for (int need = nsel; need < topk; ++need) {
        unsigned long long best = 0ULL;
        for (int i = t; i < N; i += THREADS) {
            bool taken = false;
            for (int s2 = 0; s2 < need; ++s2)
                if (selL[s2] == i) { taken = true; break; }
            if (!taken) {
                const unsigned long long pk =
                    ((unsigned long long)score_key(scores[(size_t)b * N + i]) << 32)
                    | (unsigned)(~(unsigned)i);
                if (pk > best) best = pk;
            }
        }
        red[t] = best;
        __syncthreads();
        for (int off = 128; off > 0; off >>= 1) {
            if (t < off) { if (red[t + off] > red[t]) red[t] = red[t + off]; }
            __syncthreads();
        }
        if (t == 0) selL[need] = (int)(~(unsigned)red[0]);
        __syncthreads();
    }

    float* o_feat = out;
    float* o_kpts = out + (size_t)B * topk * 256;
    float* o_idx  = out + (size_t)B * topk * 258;
    for (int e = t; e < topk * 64; e += THREADS) {
        const int j = e >> 6, q4 = e & 63;
        const int n = selL[j];
        *(float4*)&o_feat[((size_t)b * topk + j) * 256 + q4 * 4] =
            *(const float4*)&desc[((size_t)b * N + n) * 256 + q4 * 4];
    }
    for (int j = t; j < topk; j += THREADS) {
        const int n = selL[j];
        o_kpts[((size_t)b * topk + j) * 2 + 0] = kpts[((size_t)b * N + n) * 2 + 0];
        o_kpts[((size_t)b * topk + j) * 2 + 1] = kpts[((size_t)b * N + n) * 2 + 1];
        o_idx[(size_t)b * topk + j] = (float)n;
    }
}

extern "C" void kernel_launch(void* const* d_in, const int* in_sizes, int n_in,
                              void* d_out, int out_size, void* d_ws, size_t ws_size,
                              hipStream_t stream) {
    const float* kpts = (const float*)d_in[0];
    const float* desc = (const float*)d_in[1];
    const int*   Hp   = (const int*)d_in[2];
    const int*   Wp   = (const int*)d_in[3];
    const int*   tkp  = (const int*)d_in[4];
    const float* W1   = (const float*)d_in[5];
    const float* b1   = (const float*)d_in[6];
    const float* g1   = (const float*)d_in[7];
    const float* be1  = (const float*)d_in[8];
    const float* W2   = (const float*)d_in[9];
    const float* b2   = (const float*)d_in[10];
    const float* Ws   = (const float*)d_in[11];
    const float* bs   = (const float*)d_in[12];

    const int total = in_sizes[1] / 256;   // B*N
    const int BT    = out_size / 259;      // B*topk
    const int B     = BT / 128;            // topk = 128 for this problem
    const int N     = total / B;
    const int OUT   = in_sizes[11];        // 128

    float* ws_v      = (float*)d_ws;                       // 257 floats (pad 512)
    float* ws_scores = ws_v + 512;                         // total floats
    size_t off = ((size_t)(512 + total) * 4 + 255) & ~(size_t)255;
    unsigned long long* ws_bins = (unsigned long long*)((char*)d_ws + off);
    size_t off2 = (off + (size_t)B * 128 * 8 + 255) & ~(size_t)255;
    uint4* ws_wfrag = (uint4*)((char*)d_ws + off2);        // 16384 uint4 = 256KB

    prep_kernel<<<1, 256, 0, stream>>>(W2, b2, Ws, bs, ws_v, OUT);
    prep_w1frag<<<64, 256, 0, stream>>>(W1, ws_wfrag);
    init_bins<<<(B * 128 + 255) / 256, 256, 0, stream>>>(ws_bins, B * 128);
    score_kernel<<<(total + 127) / 128, 256, 0, stream>>>(
        desc, kpts, ws_wfrag, b1, g1, be1, Hp, Wp, ws_v, ws_scores, ws_bins, N, total);
    finalize_kernel<<<B, 256, 0, stream>>>(ws_scores, ws_bins, desc, kpts, tkp,
                                           (float*)d_out, B, N);
}

// Round 5
// 401.230 us; speedup vs baseline: 1.2489x; 1.2489x over previous
//
#include <hip/hip_runtime.h>
#include <hip/hip_bf16.h>

typedef short bf16x8 __attribute__((ext_vector_type(8)));
typedef float f32x16 __attribute__((ext_vector_type(16)));

__device__ __forceinline__ unsigned short f2bf(float x) {
    unsigned u = __float_as_uint(x);
    return (unsigned short)((u + 0x7FFFu + ((u >> 16) & 1u)) >> 16);
}
__device__ __forceinline__ float bf2f(unsigned short h) {
    return __uint_as_float(((unsigned)h) << 16);
}
__device__ __forceinline__ unsigned score_key(float s) {
    unsigned u = __float_as_uint(s);
    return (u & 0x80000000u) ? ~u : (u | 0x80000000u);
}

// native-cast split: f32[8] -> bf16 hi + bf16 lo
__device__ __forceinline__ void split8n(const float4& fa, const float4& fb,
                                        bf16x8& hv, bf16x8& lv) {
    const float f[8] = {fa.x, fa.y, fa.z, fa.w, fb.x, fb.y, fb.z, fb.w};
    union { unsigned short u[8]; bf16x8 v; } H, L;
#pragma unroll
    for (int j = 0; j < 8; ++j) {
        __hip_bfloat16 hb = __float2bfloat16(f[j]);
        const unsigned short hr = reinterpret_cast<const unsigned short&>(hb);
        const float hf = __uint_as_float(((unsigned)hr) << 16);
        __hip_bfloat16 lb = __float2bfloat16(f[j] - hf);
        H.u[j] = hr;
        L.u[j] = reinterpret_cast<const unsigned short&>(lb);
    }
    hv = H.v; lv = L.v;
}

__device__ __forceinline__ void async_cp16(const uint4* g, uint4* l) {
    __builtin_amdgcn_global_load_lds(
        (const __attribute__((address_space(1))) unsigned int*)g,
        (__attribute__((address_space(3))) unsigned int*)l, 16, 0, 0);
}

// v[j] = sum_o W2[j,o]*Ws[o];  v[256] = dot(b2,Ws) + bs
__global__ void prep_kernel(const float* __restrict__ W2, const float* __restrict__ b2,
                            const float* __restrict__ Ws, const float* __restrict__ bs,
                            float* __restrict__ v, int OUT) {
    int j = threadIdx.x;
    float acc = 0.f;
    for (int o = 0; o < OUT; ++o) acc += W2[j * OUT + o] * Ws[o];
    v[j] = acc;
    if (j == 0) {
        float c = bs[0];
        for (int o = 0; o < OUT; ++o) c += b2[o] * Ws[o];
        v[256] = c;
    }
}

// W1 [256][256] -> 32x32x16 fragment pack, hi/lo (identical to R4 — absmax-0 verified)
// uint4 idx = kt*2048 + (hl*16 + nt*2 + kc)*64 + lane
// elem j of slot = W1[kt*32 + kc*16 + (lane>>5)*8 + j][nt*32 + (lane&31)]
__global__ void prep_w1frag(const float* __restrict__ W1, uint4* __restrict__ wfrag) {
    const int s = blockIdx.x * 256 + threadIdx.x;   // 0..16383
    const int kt = s >> 11;
    const int c = (s >> 6) & 31;
    const int lane = s & 63;
    const int hl = c >> 4;
    const int nt = (c >> 1) & 7;
    const int kc = c & 1;
    const int col = nt * 32 + (lane & 31);
    const int k0 = kt * 32 + kc * 16 + (lane >> 5) * 8;
    unsigned pk[4];
#pragma unroll
    for (int q = 0; q < 4; ++q) {
        float x0 = W1[(size_t)(k0 + 2 * q) * 256 + col];
        float x1 = W1[(size_t)(k0 + 2 * q + 1) * 256 + col];
        unsigned short a0, a1;
        if (hl == 0) { a0 = f2bf(x0); a1 = f2bf(x1); }
        else {
            a0 = f2bf(x0 - bf2f(f2bf(x0)));
            a1 = f2bf(x1 - bf2f(f2bf(x1)));
        }
        pk[q] = (unsigned)a0 | ((unsigned)a1 << 16);
    }
    wfrag[s] = make_uint4(pk[0], pk[1], pk[2], pk[3]);
}

__global__ void init_bins(unsigned long long* __restrict__ bins, int n) {
    int i = blockIdx.x * blockDim.x + threadIdx.x;
    if (i < n) bins[i] = 0ULL;
}

// 512 threads = 8 waves = 4 rowgrp x 2 colgrp. Wave tile: 32 rows x 128 cols (acc 64 AGPR).
// A direct-from-global with cross-barrier prefetch; B async global->LDS double-buffered.
__global__ __launch_bounds__(512, 4) void score_kernel(
    const float* __restrict__ desc, const float* __restrict__ kpts,
    const uint4* __restrict__ wfrag,
    const float* __restrict__ b1, const float* __restrict__ g1, const float* __restrict__ be1,
    const int* __restrict__ Hp, const int* __restrict__ Wp,
    const float* __restrict__ v,
    float* __restrict__ scores, unsigned long long* __restrict__ bins,
    int N, int total)
{
    __shared__ uint4 BS[2][32 * 64];       // double-buffered W1 frags (2 x 32KB)
    __shared__ float b1L[256], g1L[256], beL[256], vL[256];
    __shared__ float sums2[128][4];        // [rowInBlk][cg*2 + {sx,sq}]
    __shared__ float dot2[128][2];         // [rowInBlk][cg]

    const int t = threadIdx.x;
    const int lane = t & 63;
    const int w = t >> 6;                  // wave 0..7
    const int rg = w >> 1, cg = w & 1;
    const int c31 = lane & 31;
    const int h = lane >> 5;
    const int R0 = blockIdx.x * 128 + rg * 32;
    const int C0 = cg * 128;

    if (t < 256) { b1L[t] = b1[t]; g1L[t] = g1[t]; beL[t] = be1[t]; vL[t] = v[t]; }

    // stage B[kt=0] into BS[0]: 2048 uint4, 4 per thread, wave-linear dest
    {
        const uint4* bsrc = wfrag + t;
#pragma unroll
        for (int j = 0; j < 4; ++j)
            async_cp16(bsrc + j * 512, &BS[0][j * 512 + t]);
    }

    // A: lane's row = R0 + c31; k-slots of chunk kc: kt*32 + kc*16 + h*8 + {0..7}
    const int rA = min(R0 + c31, total - 1);
    const float* pa = desc + (size_t)rA * 256 + h * 8;
    // prefetch kc0-pair of kt=0
    float4 a0A = *(const float4*)(pa + 0);
    float4 a0B = *(const float4*)(pa + 4);

    __syncthreads();   // drains vmcnt: B[0] staged, params visible

    f32x16 acc[4];
#pragma unroll
    for (int n4 = 0; n4 < 4; ++n4) {
        const float bc = b1L[C0 + n4 * 32 + c31];   // fold b1 into acc init
#pragma unroll
        for (int r = 0; r < 16; ++r) acc[n4][r] = bc;
    }

    for (int kt = 0; kt < 8; ++kt) {
        const int cur = kt & 1;
        // issue kc1-pair of this kt (consumed after kc0 compute ~1000cy later)
        const float* pc = pa + kt * 32 + 16;
        float4 a1A = *(const float4*)(pc + 0);
        float4 a1B = *(const float4*)(pc + 4);
        // issue kc0-pair of NEXT kt (consumed after the barrier)
        float4 n0A, n0B;
        if (kt < 7) {
            const float* pn = pa + (kt + 1) * 32;
            n0A = *(const float4*)(pn + 0);
            n0B = *(const float4*)(pn + 4);
        }
        // stage B[kt+1] async into alternate buffer
        if (kt < 7) {
            const uint4* bsrc = wfrag + (size_t)(kt + 1) * 2048 + t;
#pragma unroll
            for (int j = 0; j < 4; ++j)
                async_cp16(bsrc + j * 512, &BS[cur ^ 1][j * 512 + t]);
        }
        // ---- kc = 0 (A already in-register from before the barrier)
        {
            bf16x8 ah, al;
            split8n(a0A, a0B, ah, al);
            bf16x8 bh[4], bl[4];
#pragma unroll
            for (int n4 = 0; n4 < 4; ++n4) {
                const int nt = cg * 4 + n4;
                bh[n4] = *(const bf16x8*)&BS[cur][(nt * 2 + 0) * 64 + lane];
                bl[n4] = *(const bf16x8*)&BS[cur][(16 + nt * 2 + 0) * 64 + lane];
            }
#pragma unroll
            for (int n4 = 0; n4 < 4; ++n4)
                acc[n4] = __builtin_amdgcn_mfma_f32_32x32x16_bf16(ah, bh[n4], acc[n4], 0, 0, 0);
#pragma unroll
            for (int n4 = 0; n4 < 4; ++n4)
                acc[n4] = __builtin_amdgcn_mfma_f32_32x32x16_bf16(al, bh[n4], acc[n4], 0, 0, 0);
#pragma unroll
            for (int n4 = 0; n4 < 4; ++n4)
                acc[n4] = __builtin_amdgcn_mfma_f32_32x32x16_bf16(ah, bl[n4], acc[n4], 0, 0, 0);
#pragma unroll
            for (int n4 = 0; n4 < 4; ++n4)
                acc[n4] = __builtin_amdgcn_mfma_f32_32x32x16_bf16(al, bl[n4], acc[n4], 0, 0, 0);
        }
        // ---- kc = 1
        {
            bf16x8 ah, al;
            split8n(a1A, a1B, ah, al);
            bf16x8 bh[4], bl[4];
#pragma unroll
            for (int n4 = 0; n4 < 4; ++n4) {
                const int nt = cg * 4 + n4;
                bh[n4] = *(const bf16x8*)&BS[cur][(nt * 2 + 1) * 64 + lane];
                bl[n4] = *(const bf16x8*)&BS[cur][(16 + nt * 2 + 1) * 64 + lane];
            }
#pragma unroll
            for (int n4 = 0; n4 < 4; ++n4)
                acc[n4] = __builtin_amdgcn_mfma_f32_32x32x16_bf16(ah, bh[n4], acc[n4], 0, 0, 0);
#pragma unroll
            for (int n4 = 0; n4 < 4; ++n4)
                acc[n4] = __builtin_amdgcn_mfma_f32_32x32x16_bf16(al, bh[n4], acc[n4], 0, 0, 0);
#pragma unroll
            for (int n4 = 0; n4 < 4; ++n4)
                acc[n4] = __builtin_amdgcn_mfma_f32_32x32x16_bf16(ah, bl[n4], acc[n4], 0, 0, 0);
#pragma unroll
            for (int n4 = 0; n4 < 4; ++n4)
                acc[n4] = __builtin_amdgcn_mfma_f32_32x32x16_bf16(al, bl[n4], acc[n4], 0, 0, 0);
        }
        a0A = n0A; a0B = n0B;
        __syncthreads();   // next B buffer staged; prefetched A consumed next iter
    }

    // ---- epilogue. C/D: rowIn32=(reg&3)+8*(reg>>2)+4*h, col=C0+n4*32+c31
    // preload per-lane epilogue params (4 cols)
    float gE[4], beE[4], vE[4];
#pragma unroll
    for (int n4 = 0; n4 < 4; ++n4) {
        const int c = C0 + n4 * 32 + c31;
        gE[n4] = g1L[c]; beE[n4] = beL[c]; vE[n4] = vL[c];
    }
    // pass 1: per-row sx, sq over this wave's 128 cols
#pragma unroll
    for (int reg = 0; reg < 16; ++reg) {
        float sx = 0.f, sq = 0.f;
#pragma unroll
        for (int n4 = 0; n4 < 4; ++n4) {
            const float x = acc[n4][reg];
            sx += x; sq = fmaf(x, x, sq);
        }
#pragma unroll
        for (int m = 1; m <= 16; m <<= 1) {
            sx += __shfl_xor(sx, m);
            sq += __shfl_xor(sq, m);
        }
        if (c31 == 0) {
            const int rowB = rg * 32 + (reg & 3) + 8 * (reg >> 2) + 4 * h;
            sums2[rowB][cg * 2 + 0] = sx;
            sums2[rowB][cg * 2 + 1] = sq;
        }
    }
    __syncthreads();
    // pass 2: LN + SiLU + dot(v) partial
#pragma unroll
    for (int reg = 0; reg < 16; ++reg) {
        const int rowB = rg * 32 + (reg & 3) + 8 * (reg >> 2) + 4 * h;
        const float4 s4 = *(const float4*)&sums2[rowB][0];
        const float mu = (s4.x + s4.z) * (1.f / 256.f);
        const float var = (s4.y + s4.w) * (1.f / 256.f) - mu * mu;
        const float rs = 1.f / sqrtf(var + 1e-5f);
        float dot = 0.f;
#pragma unroll
        for (int n4 = 0; n4 < 4; ++n4) {
            const float hv = (acc[n4][reg] - mu) * rs * gE[n4] + beE[n4];
            const float sg = 1.f / (1.f + __expf(-hv));
            dot = fmaf(vE[n4], hv * sg, dot);
        }
#pragma unroll
        for (int m = 1; m <= 16; m <<= 1) dot += __shfl_xor(dot, m);
        if (c31 == 0) dot2[rowB][cg] = dot;
    }
    __syncthreads();
    // pass 3: one thread per row — score, gid, bin argmax
    if (t < 128) {
        const int row = blockIdx.x * 128 + t;
        if (row < total) {
            const float sc = dot2[t][0] + dot2[t][1] + v[256];
            scores[row] = sc;
            const float Wf = (float)Wp[0];
            const int Hi = Hp[0];
            const float t02 = (float)(0.2 * (double)Hi);
            const float t05 = (float)(0.5 * (double)Hi);
            const float t03 = (float)(0.3 * (double)Hi);
            const float x = kpts[(size_t)row * 2 + 0];
            const float y = kpts[(size_t)row * 2 + 1];
            int g = -1;
            if (y > t05) {
                int bgx = (int)(x / Wf * 16.f); bgx = min(max(bgx, 0), 15);
                int bgy = (int)((y - t05) / t05 * 6.f); bgy = min(max(bgy, 0), 5);
                g = 32 + bgy * 16 + bgx;
            } else if (y > t02) {
                int mgx = (int)(x / Wf * 8.f); mgx = min(max(mgx, 0), 7);
                int mgy = (int)((y - t02) / t03 * 4.f); mgy = min(max(mgy, 0), 3);
                g = mgy * 8 + mgx;
            }
            if (g >= 0) {
                const int bb = row / N;
                const int n = row - bb * N;
                const unsigned long long pk =
                    ((unsigned long long)score_key(sc) << 32) | (unsigned)(~(unsigned)n);
                atomicMax(&bins[bb * 128 + g], pk);
            }
        }
    }
}

// One block per batch: compact bin winners (bin order), top-k fallback, gather outputs.
__global__ __launch_bounds__(256) void finalize_kernel(
    const float* __restrict__ scores, const unsigned long long* __restrict__ bins,
    const float* __restrict__ desc, const float* __restrict__ kpts,
    const int* __restrict__ tkp, float* __restrict__ out, int B, int N)
{
    const int b = blockIdx.x, t = threadIdx.x;
    const int topk = tkp[0];
    __shared__ int selL[512];
    __shared__ int nselS;
    __shared__ unsigned long long red[256];
    __shared__ unsigned long long binL[128];

    if (t < 128) binL[t] = bins[b * 128 + t];
    __syncthreads();
    if (t == 0) {
        int c = 0;
        for (int i = 0; i < 128; ++i)
            if ((binL[i] >> 32) != 0ULL) selL[c++] = (int)(~(unsigned)binL[i]);
        nselS = c;
    }
    __syncthreads();
    const int nsel = nselS;

    for (int need = nsel; need < topk; ++need) {
        unsigned long long best = 0ULL;
        for (int i = t; i < N; i += 256) {
            bool taken = false;
            for (int s2 = 0; s2 < need; ++s2)
                if (selL[s2] == i) { taken = true; break; }
            if (!taken) {
                const unsigned long long pk =
                    ((unsigned long long)score_key(scores[(size_t)b * N + i]) << 32)
                    | (unsigned)(~(unsigned)i);
                if (pk > best) best = pk;
            }
        }
        red[t] = best;
        __syncthreads();
        for (int off = 128; off > 0; off >>= 1) {
            if (t < off) { if (red[t + off] > red[t]) red[t] = red[t + off]; }
            __syncthreads();
        }
        if (t == 0) selL[need] = (int)(~(unsigned)red[0]);
        __syncthreads();
    }

    float* o_feat = out;
    float* o_kpts = out + (size_t)B * topk * 256;
    float* o_idx  = out + (size_t)B * topk * 258;
    for (int e = t; e < topk * 64; e += 256) {
        const int j = e >> 6, q4 = e & 63;
        const int n = selL[j];
        *(float4*)&o_feat[((size_t)b * topk + j) * 256 + q4 * 4] =
            *(const float4*)&desc[((size_t)b * N + n) * 256 + q4 * 4];
    }
    for (int j = t; j < topk; j += 256) {
        const int n = selL[j];
        o_kpts[((size_t)b * topk + j) * 2 + 0] = kpts[((size_t)b * N + n) * 2 + 0];
        o_kpts[((size_t)b * topk + j) * 2 + 1] = kpts[((size_t)b * N + n) * 2 + 1];
        o_idx[(size_t)b * topk + j] = (float)n;
    }
}

extern "C" void kernel_launch(void* const* d_in, const int* in_sizes, int n_in,
                              void* d_out, int out_size, void* d_ws, size_t ws_size,
                              hipStream_t stream) {
    const float* kpts = (const float*)d_in[0];
    const float* desc = (const float*)d_in[1];
    const int*   Hp   = (const int*)d_in[2];
    const int*   Wp   = (const int*)d_in[3];
    const int*   tkp  = (const int*)d_in[4];
    const float* W1   = (const float*)d_in[5];
    const float* b1   = (const float*)d_in[6];
    const float* g1   = (const float*)d_in[7];
    const float* be1  = (const float*)d_in[8];
    const float* W2   = (const float*)d_in[9];
    const float* b2   = (const float*)d_in[10];
    const float* Ws   = (const float*)d_in[11];
    const float* bs   = (const float*)d_in[12];

    const int total = in_sizes[1] / 256;   // B*N
    const int BT    = out_size / 259;      // B*topk
    const int B     = BT / 128;            // topk = 128 for this problem
    const int N     = total / B;
    const int OUT   = in_sizes[11];        // 128

    float* ws_v      = (float*)d_ws;                       // 257 floats (pad 512)
    float* ws_scores = ws_v + 512;                         // total floats
    size_t off = ((size_t)(512 + total) * 4 + 255) & ~(size_t)255;
    unsigned long long* ws_bins = (unsigned long long*)((char*)d_ws + off);
    size_t off2 = (off + (size_t)B * 128 * 8 + 255) & ~(size_t)255;
    uint4* ws_wfrag = (uint4*)((char*)d_ws + off2);        // 16384 uint4 = 256KB

    prep_kernel<<<1, 256, 0, stream>>>(W2, b2, Ws, bs, ws_v, OUT);
    prep_w1frag<<<64, 256, 0, stream>>>(W1, ws_wfrag);
    init_bins<<<(B * 128 + 255) / 256, 256, 0, stream>>>(ws_bins, B * 128);
    score_kernel<<<(total + 127) / 128, 512, 0, stream>>>(
        desc, kpts, ws_wfrag, b1, g1, be1, Hp, Wp, ws_v, ws_scores, ws_bins, N, total);
    finalize_kernel<<<B, 256, 0, stream>>>(ws_scores, ws_bins, desc, kpts, tkp,
                                           (float*)d_out, B, N);
}